// Round 10
// baseline (770.097 us; speedup 1.0000x reference)
//
#include <hip/hip_runtime.h>
#include <cstdint>
#include <cstddef>

#define NPTS 500000

using f16   = _Float16;
using f16x8 = __attribute__((ext_vector_type(8))) _Float16;
using f32x4 = __attribute__((ext_vector_type(4))) float;
using f32x16= __attribute__((ext_vector_type(16))) float;

// ---- ws layout (bytes). f16 weight images, pre-transposed W^T[m][k], output rows
// phi-permuted (phi = swap bits 2<->3; double-phi cancels so image k = global k).
// in/skip images [128m][256c] (c = sin/cos K-interleaved per 16-j group) split into
// two 32KB halves BY ROW: half0 = rows 0-63 (mtiles 0,1), half1 = rows 64-127.
#define WS_INW   0u           // 2 x 32768
#define WS_SKIP  65536u       // 4 x (2 x 32768)
#define WS_W1    327680u      // 8 x 32768  [128m][128k] f16, pitch 256B
#define WS_W2    589824u      // 8 x 32768
#define WS_BIAS  851968u      // 22*128 f32: arr[M][pos] = b_M[phi(pos)]
#define WS_BC    863232u      // 256 f32: B coeffs prescaled by 1/(2pi)
#define WS_OB    864256u      // 1 f32 + pad
#define WS_TOTAL 864272u

__device__ __host__ __forceinline__ int phi(int m) {
  return (m & ~12) | ((m & 4) << 1) | ((m & 8) >> 1);
}

// ---------------- prep: pack everything into ws
extern "C" __global__ void pinn_prep(const float* __restrict__ in_w,
                                     const float* __restrict__ w1,
                                     const float* __restrict__ w2,
                                     const float* __restrict__ skw,
                                     const float* __restrict__ inb,
                                     const float* __restrict__ b1,
                                     const float* __restrict__ b2,
                                     const float* __restrict__ skb,
                                     const float* __restrict__ ow,
                                     const float* __restrict__ ob,
                                     const float* __restrict__ Bg,
                                     char* __restrict__ ws) {
  int idx = (int)blockIdx.x * 256 + (int)threadIdx.x;
  if (idx < 32768) {                       // in_w [128m][256c] -> row-halves
    int m = idx >> 8, c = idx & 255;
    int k = ((c >> 4) & 1) * 128 + (c >> 5) * 16 + (c & 15);
    int ml = m & 63;
    uint32_t off = (uint32_t)(ml * 512 + c * 2) ^ (uint32_t)((ml & 31) << 4);
    *(f16*)(ws + WS_INW + (uint32_t)(m >> 6) * 32768u + off) = (f16)in_w[k * 128 + phi(m)];
  } else if (idx < 163840) {               // skip images, same split
    int r = idx - 32768; int j4 = r >> 15; r &= 32767;
    int m = r >> 8, c = r & 255;
    int k = ((c >> 4) & 1) * 128 + (c >> 5) * 16 + (c & 15);
    int ml = m & 63;
    uint32_t off = (uint32_t)(ml * 512 + c * 2) ^ (uint32_t)((ml & 31) << 4);
    *(f16*)(ws + WS_SKIP + (uint32_t)j4 * 65536u + (uint32_t)(m >> 6) * 32768u + off) =
        (f16)skw[(j4 * 256 + k) * 128 + phi(m)];
  } else if (idx < 294912) {               // w1 [8][128m][128k]
    int r0 = idx - 163840;
    int i = r0 >> 14, r = r0 & 16383, m = r >> 7, k = r & 127;
    uint32_t off = (uint32_t)(m * 256 + k * 2) ^ (uint32_t)((m & 15) << 4);
    *(f16*)(ws + WS_W1 + (uint32_t)i * 32768u + off) = (f16)w1[(i * 128 + k) * 128 + phi(m)];
  } else if (idx < 425984) {               // w2 [8][128m][128k]
    int r0 = idx - 294912;
    int i = r0 >> 14, r = r0 & 16383, m = r >> 7, k = r & 127;
    uint32_t off = (uint32_t)(m * 256 + k * 2) ^ (uint32_t)((m & 15) << 4);
    *(f16*)(ws + WS_W2 + (uint32_t)i * 32768u + off) = (f16)w2[(i * 128 + k) * 128 + phi(m)];
  } else if (idx < 428800) {               // bias image
    int r = idx - 425984;
    int M = r >> 7, pos = r & 127;
    int pp = phi(pos);
    float v;
    if (M == 0)        v = inb[pp];
    else if (M <= 16)  { int t = M - 1; int i = t >> 1; v = (t & 1) ? b2[i * 128 + pp] : b1[i * 128 + pp]; }
    else if (M <= 20)  v = skb[(M - 17) * 128 + pp];
    else               v = ow[pp];
    *(float*)(ws + WS_BIAS + (uint32_t)r * 4u) = v;
  } else if (idx < 429056) {               // Bc coeffs: slot (g,hi): S j..j+8 | T j..j+8
    int r = idx - 428800;
    int slot = r >> 4, e2 = r & 15;
    int kq = slot >> 1, hb = slot & 1;
    int row = e2 >> 3, e = e2 & 7;
    int j = kq * 16 + hb * 8 + e;
    *(float*)(ws + WS_BC + (uint32_t)r * 4u) = Bg[row * 128 + j] * 0.15915494309189535f;
  } else if (idx == 429056) {
    *(float*)(ws + WS_OB) = ob[0];
    *(float*)(ws + WS_OB + 4) = 0.f; *(float*)(ws + WS_OB + 8) = 0.f; *(float*)(ws + WS_OB + 12) = 0.f;
  }
}

// ---------------- device math
__device__ __forceinline__ float ftanh(float x) {
  float e = __builtin_amdgcn_exp2f(x * 2.8853901817f);
  return 1.0f - 2.0f * __builtin_amdgcn_rcpf(e + 1.0f);
}
__device__ __forceinline__ float fsin_rev(float rev) {
  return __builtin_amdgcn_sinf(__builtin_amdgcn_fractf(rev));
}

// async global->LDS, 16B per lane; wave wv (0..3) covers [wv*8192, wv*8192+8192)
__device__ __forceinline__ void gll16(const char* g, char* l) {
  __builtin_amdgcn_global_load_lds((const __attribute__((address_space(1))) void*)g,
                                   (__attribute__((address_space(3))) void*)l, 16, 0, 0);
}
__device__ __forceinline__ void stage32(const char* g, char* l, int wv, int ln64) {
  const char* gs = g + wv * 8192 + ln64 * 16;
  char* ls = l + wv * 8192;
  #pragma unroll
  for (int it = 0; it < 8; ++it) gll16(gs + it * 1024, ls + it * 1024);
}

#define MFMA_(a,b,c)  __builtin_amdgcn_mfma_f32_32x32x16_f16(a,b,c,0,0,0)

// w1/w2 fragment load: pitch 256B, XOR mask 15
#define LDW(BASE, MT, KB) (*(const f16x8*)((BASE) + \
  ((((uint32_t)(MT)*32u + lnr)*256u + (uint32_t)(KB)*32u + hi16v) ^ SW16)))
// in/skip half-image fragment load: 64 rows, pitch 512B, XOR mask 31 (local mtile L)
#define LDH(BASE, L, KB) (*(const f16x8*)((BASE) + \
  ((((uint32_t)(L)*32u + lnr)*512u + (uint32_t)(KB)*32u + hi16v) ^ SW31)))

// bias acc init: same addr across lanes of a hi-half -> LDS broadcast (cheap)
#define BINIT(acc, Mi, MT) { const float* _bp = biasL + ((Mi)*128 + (MT)*32 + hi4); \
  f32x4 _q0 = *(const f32x4*)_bp;        f32x4 _q1 = *(const f32x4*)(_bp+8); \
  f32x4 _q2 = *(const f32x4*)(_bp+16);   f32x4 _q3 = *(const f32x4*)(_bp+24); \
  acc[0]=_q0[0]; acc[1]=_q0[1]; acc[2]=_q0[2]; acc[3]=_q0[3]; \
  acc[4]=_q1[0]; acc[5]=_q1[1]; acc[6]=_q1[2]; acc[7]=_q1[3]; \
  acc[8]=_q2[0]; acc[9]=_q2[1]; acc[10]=_q2[2]; acc[11]=_q2[3]; \
  acc[12]=_q3[0]; acc[13]=_q3[1]; acc[14]=_q3[2]; acc[15]=_q3[3]; }

#define UNPADD(acc, F0, F1) { \
  acc[0]+=(float)F0[0]; acc[1]+=(float)F0[1]; acc[2]+=(float)F0[2]; acc[3]+=(float)F0[3]; \
  acc[4]+=(float)F0[4]; acc[5]+=(float)F0[5]; acc[6]+=(float)F0[6]; acc[7]+=(float)F0[7]; \
  acc[8]+=(float)F1[0]; acc[9]+=(float)F1[1]; acc[10]+=(float)F1[2]; acc[11]+=(float)F1[3]; \
  acc[12]+=(float)F1[4]; acc[13]+=(float)F1[5]; acc[14]+=(float)F1[6]; acc[15]+=(float)F1[7]; }

#define FPACK(F0, F1, acc) { f16x8 _g0, _g1; \
  _g0[0]=(f16)acc[0]; _g0[1]=(f16)acc[1]; _g0[2]=(f16)acc[2]; _g0[3]=(f16)acc[3]; \
  _g0[4]=(f16)acc[4]; _g0[5]=(f16)acc[5]; _g0[6]=(f16)acc[6]; _g0[7]=(f16)acc[7]; \
  _g1[0]=(f16)acc[8]; _g1[1]=(f16)acc[9]; _g1[2]=(f16)acc[10]; _g1[3]=(f16)acc[11]; \
  _g1[4]=(f16)acc[12]; _g1[5]=(f16)acc[13]; _g1[6]=(f16)acc[14]; _g1[7]=(f16)acc[15]; \
  F0=_g0; F1=_g1; }

#define TPACK(F0, F1, acc) { f16x8 _g0, _g1; \
  _g0[0]=(f16)ftanh(acc[0]); _g0[1]=(f16)ftanh(acc[1]); _g0[2]=(f16)ftanh(acc[2]); _g0[3]=(f16)ftanh(acc[3]); \
  _g0[4]=(f16)ftanh(acc[4]); _g0[5]=(f16)ftanh(acc[5]); _g0[6]=(f16)ftanh(acc[6]); _g0[7]=(f16)ftanh(acc[7]); \
  _g1[0]=(f16)ftanh(acc[8]); _g1[1]=(f16)ftanh(acc[9]); _g1[2]=(f16)ftanh(acc[10]); _g1[3]=(f16)ftanh(acc[11]); \
  _g1[4]=(f16)ftanh(acc[12]); _g1[5]=(f16)ftanh(acc[13]); _g1[6]=(f16)ftanh(acc[14]); _g1[7]=(f16)ftanh(acc[15]); \
  F0=_g0; F1=_g1; }

#define OM2PI 4.7746482927f
#define SINPACK(F0, F1, acc) { f16x8 _g0, _g1; \
  _g0[0]=(f16)fsin_rev(acc[0]*OM2PI); _g0[1]=(f16)fsin_rev(acc[1]*OM2PI); \
  _g0[2]=(f16)fsin_rev(acc[2]*OM2PI); _g0[3]=(f16)fsin_rev(acc[3]*OM2PI); \
  _g0[4]=(f16)fsin_rev(acc[4]*OM2PI); _g0[5]=(f16)fsin_rev(acc[5]*OM2PI); \
  _g0[6]=(f16)fsin_rev(acc[6]*OM2PI); _g0[7]=(f16)fsin_rev(acc[7]*OM2PI); \
  _g1[0]=(f16)fsin_rev(acc[8]*OM2PI); _g1[1]=(f16)fsin_rev(acc[9]*OM2PI); \
  _g1[2]=(f16)fsin_rev(acc[10]*OM2PI); _g1[3]=(f16)fsin_rev(acc[11]*OM2PI); \
  _g1[4]=(f16)fsin_rev(acc[12]*OM2PI); _g1[5]=(f16)fsin_rev(acc[13]*OM2PI); \
  _g1[6]=(f16)fsin_rev(acc[14]*OM2PI); _g1[7]=(f16)fsin_rev(acc[15]*OM2PI); \
  F0=_g0; F1=_g1; }

// trig for feature slot ei, BOTH points of this lane (coeffs loaded once)
#define FFEP(ei, CA, CB) { \
  float _r0 = __builtin_amdgcn_fractf(s0v*(CA) + t0v*(CB)); \
  _sA[ei]=(f16)__builtin_amdgcn_sinf(_r0); _cA[ei]=(f16)__builtin_amdgcn_cosf(_r0); \
  float _r1 = __builtin_amdgcn_fractf(s1v*(CA) + t1v*(CB)); \
  _sB[ei]=(f16)__builtin_amdgcn_sinf(_r1); _cB[ei]=(f16)__builtin_amdgcn_cosf(_r1); }

// one Fourier group: 4 LDS reads (2 local mtiles x sin/cos), 8 MFMAs, trig once
#define FFG64(G, BASE) { \
  f16x8 _sA,_cA,_sB,_cB; \
  { const float* _cp = BcL + ((G)*2 + hi)*16; \
    f32x4 _a0 = *(const f32x4*)_cp, _a1 = *(const f32x4*)(_cp+4); \
    f32x4 _b0 = *(const f32x4*)(_cp+8), _b1 = *(const f32x4*)(_cp+12); \
    FFEP(0,_a0[0],_b0[0]) FFEP(1,_a0[1],_b0[1]) FFEP(2,_a0[2],_b0[2]) FFEP(3,_a0[3],_b0[3]) \
    FFEP(4,_a1[0],_b1[0]) FFEP(5,_a1[1],_b1[1]) FFEP(6,_a1[2],_b1[2]) FFEP(7,_a1[3],_b1[3]) } \
  { f16x8 _w = LDH(BASE,0,(G)*2);   a00=MFMA_(_w,_sA,a00); a01=MFMA_(_w,_sB,a01); } \
  { f16x8 _w = LDH(BASE,0,(G)*2+1); a00=MFMA_(_w,_cA,a00); a01=MFMA_(_w,_cB,a01); } \
  { f16x8 _w = LDH(BASE,1,(G)*2);   a10=MFMA_(_w,_sA,a10); a11=MFMA_(_w,_sB,a11); } \
  { f16x8 _w = LDH(BASE,1,(G)*2+1); a10=MFMA_(_w,_cA,a10); a11=MFMA_(_w,_cB,a11); } }

// ff matmul pass over one ROW-HALF (global mtiles MTA, MTA+1), both pt-groups.
// Reads ONLY `BASE` (one slot) -> staging of the other slot overlaps freely.
#define FFPASS(MTA, MI, X00,X01, Y00,Y01, X10,X11, Y10,Y11, RES, SINEPI, BASE) { \
  f32x16 a00; BINIT(a00, MI, MTA)       f32x16 a01 = a00; \
  f32x16 a10; BINIT(a10, MI, (MTA)+1)   f32x16 a11 = a10; \
  if (RES) { UNPADD(a00, X00,X01) UNPADD(a01, Y00,Y01) \
             UNPADD(a10, X10,X11) UNPADD(a11, Y10,Y11) } \
  FFG64(0,BASE) FFG64(1,BASE) FFG64(2,BASE) FFG64(3,BASE) \
  FFG64(4,BASE) FFG64(5,BASE) FFG64(6,BASE) FFG64(7,BASE) \
  if (SINEPI) { SINPACK(X00,X01,a00) SINPACK(Y00,Y01,a01) \
                SINPACK(X10,X11,a10) SINPACK(Y10,Y11,a11) } \
  else        { FPACK(X00,X01,a00) FPACK(Y00,Y01,a01) \
                FPACK(X10,X11,a10) FPACK(Y10,Y11,a11) } }

#define W1K(kb) { f16x8 _a = LDW(sA_, MTv, kb); \
  acc0 = MFMA_(_a, xA##kb, acc0); acc1 = MFMA_(_a, xB##kb, acc1); }
#define W1TILE(MT, UA0_, UA1_, UB0_, UB1_) { const uint32_t MTv = (MT); \
  f32x16 acc0; BINIT(acc0, Mw1, MT) f32x16 acc1 = acc0; \
  W1K(0) W1K(1) W1K(2) W1K(3) W1K(4) W1K(5) W1K(6) W1K(7) \
  TPACK(UA0_, UA1_, acc0) TPACK(UB0_, UB1_, acc1) }

#define W2K(kb) { f16x8 _a = LDW(sB_, MTv, kb); \
  acc0 = MFMA_(_a, uA##kb, acc0); acc1 = MFMA_(_a, uB##kb, acc1); }
#define W2TILE(MT, XA0_, XA1_, XB0_, XB1_) { const uint32_t MTv = (MT); \
  f32x16 acc0; BINIT(acc0, Mw2, MT) f32x16 acc1 = acc0; \
  UNPADD(acc0, XA0_, XA1_) UNPADD(acc1, XB0_, XB1_) \
  W2K(0) W2K(1) W2K(2) W2K(3) W2K(4) W2K(5) W2K(6) W2K(7) \
  FPACK(XA0_, XA1_, acc0) FPACK(XB0_, XB1_, acc1) }

#define OWDOT(P, F0, F1, bp) P += (float)F0[0]*bp[0] + (float)F0[1]*bp[1] + (float)F0[2]*bp[2] + (float)F0[3]*bp[3] \
  + (float)F0[4]*bp[8]  + (float)F0[5]*bp[9]  + (float)F0[6]*bp[10] + (float)F0[7]*bp[11] \
  + (float)F1[0]*bp[16] + (float)F1[1]*bp[17] + (float)F1[2]*bp[18] + (float)F1[3]*bp[19] \
  + (float)F1[4]*bp[24] + (float)F1[5]*bp[25] + (float)F1[6]*bp[26] + (float)F1[7]*bp[27];

// ---------------- main: 256 thr = 4 waves x 64 pts = 256 pts/block; 2 blocks/CU
// (LDS 77.8KB). 4-wave blocks are the shape where this toolchain allocates >128
// VGPRs (m97: 164; attn: 205-249); 512-thread blocks empirically cap at 128
// (R2/R8/R9: cap = 256/launch_bounds_arg). __launch_bounds__(256,2): 2 blocks/CU
// -> 2 waves/SIMD -> 256-reg budget; demand ~200 -> zero spills.
extern "C" __global__ void __launch_bounds__(256, 2)
pinn_main(const float* __restrict__ Sg, const float* __restrict__ Tg,
          const char* __restrict__ ws, float* __restrict__ outg)
{
  extern __shared__ char smem[];     // sA 32K | sB 32K | bias 12.3K
  char* sAw = smem;          const char* sA_ = sAw;
  char* sBw = smem + 32768;  const char* sB_ = sBw;
  const float* biasL = (const float*)(smem + 65536);
  const float* BcL   = biasL + 2816;

  const int tid  = (int)threadIdx.x;
  const int lane = tid & 63;
  const int wave = tid >> 6;         // 0..3
  const int hi   = lane >> 5;
  const uint32_t lnr   = (uint32_t)(lane & 31);
  const uint32_t hi16v = (uint32_t)hi * 16u;
  const uint32_t SW16  = (lnr & 15u) << 4;
  const uint32_t SW31  = lnr << 4;
  const int hi4  = hi * 4;

  // this lane's TWO points (2 lanes per point via hi-split of K)
  const int pb = (int)blockIdx.x * 256 + wave * 64 + (int)lnr;
  const int q0 = pb      < NPTS ? pb      : NPTS - 1;
  const int q1 = pb + 32 < NPTS ? pb + 32 : NPTS - 1;
  const float s0v = Sg[q0], t0v = Tg[q0];
  const float s1v = Sg[q1], t1v = Tg[q1];

  // prologue: bias image (plain vector copy) + in halves (async)
  #pragma unroll 1
  for (int o = tid * 16; o < 12304; o += 4096)
    *(f32x4*)(smem + 65536 + o) = *(const f32x4*)(ws + WS_BIAS + o);
  stage32(ws + WS_INW,          sAw, wave, lane);
  stage32(ws + WS_INW + 32768u, sBw, wave, lane);
  __syncthreads();

  // x fragments: 16 x f16x8 = 64 VGPRs, the long-lived state
  f16x8 xA0,xA1,xA2,xA3,xA4,xA5,xA6,xA7, xB0,xB1,xB2,xB3,xB4,xB5,xB6,xB7;

  // ---- input layer: x = sin(30*(ff @ in_w + in_b)); pass per row-half
  FFPASS(0, 0, xA0,xA1, xB0,xB1, xA2,xA3, xB2,xB3, 0, 1, sA_)
  __syncthreads();
  stage32(ws + WS_W1, sAw, wave, lane);
  FFPASS(2, 0, xA4,xA5, xB4,xB5, xA6,xA7, xB6,xB7, 0, 1, sB_)
  __syncthreads();
  stage32(ws + WS_W2, sBw, wave, lane);

  // ---- residual blocks
  #pragma unroll 1
  for (int i = 0; i < 8; ++i) {
    const int Mw1 = 1 + 2 * i, Mw2 = 2 + 2 * i;
    f16x8 uA0,uA1,uA2,uA3,uA4,uA5,uA6,uA7, uB0,uB1,uB2,uB3,uB4,uB5,uB6,uB7;

    __syncthreads();                          // staged sA(w1_i)/sB(w2_i) ready
    W1TILE(0, uA0,uA1, uB0,uB1)
    W1TILE(1, uA2,uA3, uB2,uB3)
    W1TILE(2, uA4,uA5, uB4,uB5)
    W1TILE(3, uA6,uA7, uB6,uB7)
    __syncthreads();                          // sA reads done
    if ((i & 1) == 0) stage32(ws + WS_SKIP + (uint32_t)(i >> 1) * 65536u, sAw, wave, lane);
    else if (i < 7)   stage32(ws + WS_W1 + (uint32_t)(i + 1) * 32768u, sAw, wave, lane);

    W2TILE(0, xA0,xA1, xB0,xB1)
    W2TILE(1, xA2,xA3, xB2,xB3)
    W2TILE(2, xA4,xA5, xB4,xB5)
    W2TILE(3, xA6,xA7, xB6,xB7)
    __syncthreads();                          // sB reads done
    if ((i & 1) == 0) stage32(ws + WS_SKIP + (uint32_t)(i >> 1) * 65536u + 32768u, sBw, wave, lane);
    else if (i < 7)   stage32(ws + WS_W2 + (uint32_t)(i + 1) * 32768u, sBw, wave, lane);

    if ((i & 1) == 0) {                       // skip from Fourier features
      const int Msk = 17 + (i >> 1);
      __syncthreads();                        // both skip halves staged+drained
      FFPASS(0, Msk, xA0,xA1, xB0,xB1, xA2,xA3, xB2,xB3, 1, 0, sA_)
      __syncthreads();                        // sA reads done
      stage32(ws + WS_W1 + (uint32_t)(i + 1) * 32768u, sAw, wave, lane);
      FFPASS(2, Msk, xA4,xA5, xB4,xB5, xA6,xA7, xB6,xB7, 1, 0, sB_)
      __syncthreads();                        // sB reads done
      stage32(ws + WS_W2 + (uint32_t)(i + 1) * 32768u, sBw, wave, lane);
    }
  }

  // ---- output: out = x @ out_w + out_b (2 lanes/pt: fold hi halves)
  float p0 = 0.0f, p1 = 0.0f;
  { const float* bp = biasL + 21 * 128 + 0 * 32 + hi4; OWDOT(p0, xA0, xA1, bp) OWDOT(p1, xB0, xB1, bp) }
  { const float* bp = biasL + 21 * 128 + 1 * 32 + hi4; OWDOT(p0, xA2, xA3, bp) OWDOT(p1, xB2, xB3, bp) }
  { const float* bp = biasL + 21 * 128 + 2 * 32 + hi4; OWDOT(p0, xA4, xA5, bp) OWDOT(p1, xB4, xB5, bp) }
  { const float* bp = biasL + 21 * 128 + 3 * 32 + hi4; OWDOT(p0, xA6, xA7, bp) OWDOT(p1, xB6, xB7, bp) }
  p0 += __shfl_xor(p0, 32);
  p1 += __shfl_xor(p1, 32);
  const float obv = biasL[3072];
  if (hi == 0) {
    if (pb < NPTS)      outg[pb]      = p0 + obv;
    if (pb + 32 < NPTS) outg[pb + 32] = p1 + obv;
  }
}

extern "C" void kernel_launch(void* const* d_in, const int* in_sizes, int n_in,
                              void* d_out, int out_size, void* d_ws, size_t ws_size,
                              hipStream_t stream) {
  (void)in_sizes; (void)n_in; (void)out_size;
  const float* S   = (const float*)d_in[0];
  const float* T   = (const float*)d_in[1];
  const float* B   = (const float*)d_in[2];
  const float* inw = (const float*)d_in[3];
  const float* inb = (const float*)d_in[4];
  const float* w1  = (const float*)d_in[5];
  const float* b1  = (const float*)d_in[6];
  const float* w2  = (const float*)d_in[7];
  const float* b2  = (const float*)d_in[8];
  const float* sw  = (const float*)d_in[9];
  const float* sb  = (const float*)d_in[10];
  const float* ow  = (const float*)d_in[11];
  const float* ob  = (const float*)d_in[12];
  char* ws   = (char*)d_ws;
  float* out = (float*)d_out;
  if (ws_size < (size_t)WS_TOTAL) return;

  pinn_prep<<<1677, 256, 0, stream>>>(inw, w1, w2, sw, inb, b1, b2, sb, ow, ob, B, ws);

  const int smem_bytes = 77840;   // 32K + 32K + 12.3K -> 2 blocks/CU
  hipFuncSetAttribute(reinterpret_cast<const void*>(pinn_main),
                      hipFuncAttributeMaxDynamicSharedMemorySize, smem_bytes);
  const int grid = (NPTS + 255) / 256;   // 1954
  pinn_main<<<grid, 256, smem_bytes, stream>>>(S, T, ws, out);
}

// Round 11
// 533.224 us; speedup vs baseline: 1.4442x; 1.4442x over previous
//
#include <hip/hip_runtime.h>
#include <cstdint>
#include <cstddef>

#define NPTS 500000

using f16   = _Float16;
using f16x8 = __attribute__((ext_vector_type(8))) _Float16;
using f32x4 = __attribute__((ext_vector_type(4))) float;
using f32x16= __attribute__((ext_vector_type(16))) float;

// ---- ws layout (bytes). f16 weight images, pre-transposed W^T[m][k], output rows
// phi-permuted (phi = swap bits 2<->3; double-phi cancels so image k = global k).
// in/skip split into two 32KB halves (groups 0-3 / 4-7, sin/cos K-interleaved).
#define WS_INW   0u           // 2 x 32768
#define WS_SKIP  65536u       // 4 x 65536
#define WS_W1    327680u      // 8 x 32768  [128m][128k] f16, pitch 256B
#define WS_W2    589824u      // 8 x 32768  [128m][128k] f16
#define WS_BIAS  851968u      // 22*128 f32: arr[M][pos] = b_M[phi(pos)]
#define WS_BC    863232u      // 256 f32: B coeffs prescaled by 1/(2pi)
#define WS_OB    864256u      // 1 f32 + pad
#define WS_TOTAL 864272u

__device__ __host__ __forceinline__ int phi(int m) {
  return (m & ~12) | ((m & 4) << 1) | ((m & 8) >> 1);
}

// ---------------- prep: pack everything into ws
extern "C" __global__ void pinn_prep(const float* __restrict__ in_w,
                                     const float* __restrict__ w1,
                                     const float* __restrict__ w2,
                                     const float* __restrict__ skw,
                                     const float* __restrict__ inb,
                                     const float* __restrict__ b1,
                                     const float* __restrict__ b2,
                                     const float* __restrict__ skb,
                                     const float* __restrict__ ow,
                                     const float* __restrict__ ob,
                                     const float* __restrict__ Bg,
                                     char* __restrict__ ws) {
  int idx = (int)blockIdx.x * 256 + (int)threadIdx.x;
  if (idx < 32768) {                       // in_w halves [2][128m][128c]
    int H = idx >> 14, r = idx & 16383, m = r >> 7, c = r & 127;
    int gl = c >> 5, sc = (c >> 4) & 1, lo = c & 15;
    int k = sc * 128 + (H * 4 + gl) * 16 + lo;
    uint32_t off = (uint32_t)(m * 256 + c * 2) ^ (uint32_t)((m & 15) << 4);
    *(f16*)(ws + WS_INW + (uint32_t)H * 32768u + off) = (f16)in_w[k * 128 + phi(m)];
  } else if (idx < 163840) {               // skip halves [4][2][128][128]
    int r0 = idx - 32768;
    int j4 = r0 >> 15, rr = r0 & 32767;
    int H = rr >> 14, r = rr & 16383, m = r >> 7, c = r & 127;
    int gl = c >> 5, sc = (c >> 4) & 1, lo = c & 15;
    int k = sc * 128 + (H * 4 + gl) * 16 + lo;
    uint32_t off = (uint32_t)(m * 256 + c * 2) ^ (uint32_t)((m & 15) << 4);
    *(f16*)(ws + WS_SKIP + (uint32_t)j4 * 65536u + (uint32_t)H * 32768u + off) =
        (f16)skw[(j4 * 256 + k) * 128 + phi(m)];
  } else if (idx < 294912) {               // w1 [8][128m][128k]
    int r0 = idx - 163840;
    int i = r0 >> 14, r = r0 & 16383, m = r >> 7, k = r & 127;
    uint32_t off = (uint32_t)(m * 256 + k * 2) ^ (uint32_t)((m & 15) << 4);
    *(f16*)(ws + WS_W1 + (uint32_t)i * 32768u + off) = (f16)w1[(i * 128 + k) * 128 + phi(m)];
  } else if (idx < 425984) {               // w2 [8][128m][128k] f16
    int r0 = idx - 294912;
    int i = r0 >> 14, r = r0 & 16383, m = r >> 7, k = r & 127;
    uint32_t off = (uint32_t)(m * 256 + k * 2) ^ (uint32_t)((m & 15) << 4);
    *(f16*)(ws + WS_W2 + (uint32_t)i * 32768u + off) = (f16)w2[(i * 128 + k) * 128 + phi(m)];
  } else if (idx < 428800) {               // bias image
    int r = idx - 425984;
    int M = r >> 7, pos = r & 127;
    int pp = phi(pos);
    float v;
    if (M == 0)        v = inb[pp];
    else if (M <= 16)  { int t = M - 1; int i = t >> 1; v = (t & 1) ? b2[i * 128 + pp] : b1[i * 128 + pp]; }
    else if (M <= 20)  v = skb[(M - 17) * 128 + pp];
    else               v = ow[pp];
    *(float*)(ws + WS_BIAS + (uint32_t)r * 4u) = v;
  } else if (idx < 429056) {               // Bc coeffs: slot (g,hi): row0 j..j+8, row1 j..j+8
    int r = idx - 428800;
    int slot = r >> 4, e2 = r & 15;
    int kq = slot >> 1, hb = slot & 1;
    int row = e2 >> 3, e = e2 & 7;
    int j = kq * 16 + hb * 8 + e;
    *(float*)(ws + WS_BC + (uint32_t)r * 4u) = Bg[row * 128 + j] * 0.15915494309189535f;
  } else if (idx == 429056) {
    *(float*)(ws + WS_OB) = ob[0];
    *(float*)(ws + WS_OB + 4) = 0.f; *(float*)(ws + WS_OB + 8) = 0.f; *(float*)(ws + WS_OB + 12) = 0.f;
  }
}

// ---------------- device math
__device__ __forceinline__ float ftanh(float x) {
  float e = __builtin_amdgcn_exp2f(x * 2.8853901817f);
  return 1.0f - 2.0f * __builtin_amdgcn_rcpf(e + 1.0f);
}
__device__ __forceinline__ float fsin_rev(float rev) {
  return __builtin_amdgcn_sinf(__builtin_amdgcn_fractf(rev));
}

// async global->LDS, 16B per lane; wave wv covers [wv*4096, wv*4096+4096)
__device__ __forceinline__ void gll16(const char* g, char* l) {
  __builtin_amdgcn_global_load_lds((const __attribute__((address_space(1))) void*)g,
                                   (__attribute__((address_space(3))) void*)l, 16, 0, 0);
}
__device__ __forceinline__ void stage32(const char* g, char* l, int wv, int ln64) {
  const char* gs = g + wv * 4096 + ln64 * 16;
  char* ls = l + wv * 4096;
  #pragma unroll
  for (int it = 0; it < 4; ++it) gll16(gs + it * 1024, ls + it * 1024);
}

#define MFMA_(a,b,c)  __builtin_amdgcn_mfma_f32_32x32x16_f16(a,b,c,0,0,0)

// f16 image fragment load: pitch 256B, XOR mask 15
#define LDW(BASE, MT, KB) (*(const f16x8*)((BASE) + \
  ((((uint32_t)(MT)*32u + lnr)*256u + (uint32_t)(KB)*32u + hi16v) ^ SW16)))

// bias acc init: same addr across lanes of a hi-half -> LDS broadcast (cheap)
#define BINIT(acc, Mi, MT) { const float* _bp = biasL + ((Mi)*128 + (MT)*32 + hi4); \
  f32x4 _q0 = *(const f32x4*)_bp;        f32x4 _q1 = *(const f32x4*)(_bp+8); \
  f32x4 _q2 = *(const f32x4*)(_bp+16);   f32x4 _q3 = *(const f32x4*)(_bp+24); \
  acc[0]=_q0[0]; acc[1]=_q0[1]; acc[2]=_q0[2]; acc[3]=_q0[3]; \
  acc[4]=_q1[0]; acc[5]=_q1[1]; acc[6]=_q1[2]; acc[7]=_q1[3]; \
  acc[8]=_q2[0]; acc[9]=_q2[1]; acc[10]=_q2[2]; acc[11]=_q2[3]; \
  acc[12]=_q3[0]; acc[13]=_q3[1]; acc[14]=_q3[2]; acc[15]=_q3[3]; }

#define UNPADD(acc, F0, F1) { \
  acc[0]+=(float)F0[0]; acc[1]+=(float)F0[1]; acc[2]+=(float)F0[2]; acc[3]+=(float)F0[3]; \
  acc[4]+=(float)F0[4]; acc[5]+=(float)F0[5]; acc[6]+=(float)F0[6]; acc[7]+=(float)F0[7]; \
  acc[8]+=(float)F1[0]; acc[9]+=(float)F1[1]; acc[10]+=(float)F1[2]; acc[11]+=(float)F1[3]; \
  acc[12]+=(float)F1[4]; acc[13]+=(float)F1[5]; acc[14]+=(float)F1[6]; acc[15]+=(float)F1[7]; }

#define FPACK(F0, F1, acc) { f16x8 _g0, _g1; \
  _g0[0]=(f16)acc[0]; _g0[1]=(f16)acc[1]; _g0[2]=(f16)acc[2]; _g0[3]=(f16)acc[3]; \
  _g0[4]=(f16)acc[4]; _g0[5]=(f16)acc[5]; _g0[6]=(f16)acc[6]; _g0[7]=(f16)acc[7]; \
  _g1[0]=(f16)acc[8]; _g1[1]=(f16)acc[9]; _g1[2]=(f16)acc[10]; _g1[3]=(f16)acc[11]; \
  _g1[4]=(f16)acc[12]; _g1[5]=(f16)acc[13]; _g1[6]=(f16)acc[14]; _g1[7]=(f16)acc[15]; \
  F0=_g0; F1=_g1; }

#define TPACK(F0, F1, acc) { f16x8 _g0, _g1; \
  _g0[0]=(f16)ftanh(acc[0]); _g0[1]=(f16)ftanh(acc[1]); _g0[2]=(f16)ftanh(acc[2]); _g0[3]=(f16)ftanh(acc[3]); \
  _g0[4]=(f16)ftanh(acc[4]); _g0[5]=(f16)ftanh(acc[5]); _g0[6]=(f16)ftanh(acc[6]); _g0[7]=(f16)ftanh(acc[7]); \
  _g1[0]=(f16)ftanh(acc[8]); _g1[1]=(f16)ftanh(acc[9]); _g1[2]=(f16)ftanh(acc[10]); _g1[3]=(f16)ftanh(acc[11]); \
  _g1[4]=(f16)ftanh(acc[12]); _g1[5]=(f16)ftanh(acc[13]); _g1[6]=(f16)ftanh(acc[14]); _g1[7]=(f16)ftanh(acc[15]); \
  F0=_g0; F1=_g1; }

#define OM2PI 4.7746482927f
#define SINPACK(F0, F1, acc) { f16x8 _g0, _g1; \
  _g0[0]=(f16)fsin_rev(acc[0]*OM2PI); _g0[1]=(f16)fsin_rev(acc[1]*OM2PI); \
  _g0[2]=(f16)fsin_rev(acc[2]*OM2PI); _g0[3]=(f16)fsin_rev(acc[3]*OM2PI); \
  _g0[4]=(f16)fsin_rev(acc[4]*OM2PI); _g0[5]=(f16)fsin_rev(acc[5]*OM2PI); \
  _g0[6]=(f16)fsin_rev(acc[6]*OM2PI); _g0[7]=(f16)fsin_rev(acc[7]*OM2PI); \
  _g1[0]=(f16)fsin_rev(acc[8]*OM2PI); _g1[1]=(f16)fsin_rev(acc[9]*OM2PI); \
  _g1[2]=(f16)fsin_rev(acc[10]*OM2PI); _g1[3]=(f16)fsin_rev(acc[11]*OM2PI); \
  _g1[4]=(f16)fsin_rev(acc[12]*OM2PI); _g1[5]=(f16)fsin_rev(acc[13]*OM2PI); \
  _g1[6]=(f16)fsin_rev(acc[14]*OM2PI); _g1[7]=(f16)fsin_rev(acc[15]*OM2PI); \
  F0=_g0; F1=_g1; }

// trig for feature slot ei of this lane's ONE point (sv,tv)
#define FFE(ei, CA, CB) { \
  float _r = __builtin_amdgcn_fractf(sv*(CA) + tv*(CB)); \
  _s[ei] = (f16)__builtin_amdgcn_sinf(_r); _c[ei] = (f16)__builtin_amdgcn_cosf(_r); }
#define FF2(G, FS, FC) { const float* _cp = BcL + ((G)*2 + hi)*16; \
  f32x4 _a0 = *(const f32x4*)_cp, _a1 = *(const f32x4*)(_cp+4); \
  f32x4 _b0 = *(const f32x4*)(_cp+8), _b1 = *(const f32x4*)(_cp+12); \
  f16x8 _s, _c; \
  FFE(0,_a0[0],_b0[0]) FFE(1,_a0[1],_b0[1]) FFE(2,_a0[2],_b0[2]) FFE(3,_a0[3],_b0[3]) \
  FFE(4,_a1[0],_b1[0]) FFE(5,_a1[1],_b1[1]) FFE(6,_a1[2],_b1[2]) FFE(7,_a1[3],_b1[3]) \
  FS = _s; FC = _c; }

// one Fourier group into all 4 mtile accs (trig computed ONCE per layer per g)
#define FFG(G, SLOT) { f16x8 _fs,_fc; FF2(G,_fs,_fc) \
  { f16x8 _w=LDW(SLOT,0,((G)&3)*2);   a0=MFMA_(_w,_fs,a0); } \
  { f16x8 _w=LDW(SLOT,0,((G)&3)*2+1); a0=MFMA_(_w,_fc,a0); } \
  { f16x8 _w=LDW(SLOT,1,((G)&3)*2);   a1=MFMA_(_w,_fs,a1); } \
  { f16x8 _w=LDW(SLOT,1,((G)&3)*2+1); a1=MFMA_(_w,_fc,a1); } \
  { f16x8 _w=LDW(SLOT,2,((G)&3)*2);   a2=MFMA_(_w,_fs,a2); } \
  { f16x8 _w=LDW(SLOT,2,((G)&3)*2+1); a2=MFMA_(_w,_fc,a2); } \
  { f16x8 _w=LDW(SLOT,3,((G)&3)*2);   a3=MFMA_(_w,_fs,a3); } \
  { f16x8 _w=LDW(SLOT,3,((G)&3)*2+1); a3=MFMA_(_w,_fc,a3); } }

#define W1K(kb) { f16x8 _a = LDW(sA_, MTv, kb); acc = MFMA_(_a, x##kb, acc); }
#define W1TILE(MT, U0, U1) { const uint32_t MTv = (MT); \
  f32x16 acc; BINIT(acc, Mw1, MT) \
  W1K(0) W1K(1) W1K(2) W1K(3) W1K(4) W1K(5) W1K(6) W1K(7) \
  TPACK(U0, U1, acc) }

#define W2K(kb) { f16x8 _a = LDW(sB_, MTv, kb); acc = MFMA_(_a, u##kb, acc); }
#define W2TILE(MT, X0, X1) { const uint32_t MTv = (MT); \
  f32x16 acc; BINIT(acc, Mw2, MT) \
  W2K(0) W2K(1) W2K(2) W2K(3) W2K(4) W2K(5) W2K(6) W2K(7) \
  f16x8 _t0,_t1; FPACK(_t0,_t1,acc) X0 = X0 + _t0; X1 = X1 + _t1; }   // v_pk_add_f16

#define OWDOT(P, F0, F1, bp) P += (float)F0[0]*bp[0] + (float)F0[1]*bp[1] + (float)F0[2]*bp[2] + (float)F0[3]*bp[3] \
  + (float)F0[4]*bp[8]  + (float)F0[5]*bp[9]  + (float)F0[6]*bp[10] + (float)F0[7]*bp[11] \
  + (float)F1[0]*bp[16] + (float)F1[1]*bp[17] + (float)F1[2]*bp[18] + (float)F1[3]*bp[19] \
  + (float)F1[4]*bp[24] + (float)F1[5]*bp[25] + (float)F1[6]*bp[26] + (float)F1[7]*bp[27];

// ---------------- main: 512 thr = 8 waves x 32 pts = 256 pts/block; 2 blocks/CU
// (LDS 77.8KB) = 4 waves/SIMD. __launch_bounds__(512, 2): VGPR cap 128 (measured
// toolchain rule: cap = 256/arg, hard ceiling 128 — R2..R10). Peak demand ~116
// (FF: 4 accs 64 + x 32 + temps; W1/W2: x32+u32+acc16) -> spill-free at cap 128.
// R8 identical structure at (512,4) capped 64 -> 407MB spill; this is the fix.
extern "C" __global__ void __launch_bounds__(512, 2)
pinn_main(const float* __restrict__ Sg, const float* __restrict__ Tg,
          const char* __restrict__ ws, float* __restrict__ outg)
{
  extern __shared__ char smem[];     // sA 32K | sB 32K | bias 12.3K
  char* sAw = smem;          const char* sA_ = sAw;
  char* sBw = smem + 32768;  const char* sB_ = sBw;
  const float* biasL = (const float*)(smem + 65536);
  const float* BcL   = biasL + 2816;

  const int tid  = (int)threadIdx.x;
  const int lane = tid & 63;
  const int wave = tid >> 6;
  const int hi   = lane >> 5;
  const uint32_t lnr   = (uint32_t)(lane & 31);
  const uint32_t hi16v = (uint32_t)hi * 16u;
  const uint32_t SW16  = (lnr & 15u) << 4;
  const int hi4  = hi * 4;

  // this lane's ONE point (2 lanes per point via hi-split of K)
  const int pt = (int)blockIdx.x * 256 + wave * 32 + (int)lnr;
  const int q  = pt < NPTS ? pt : NPTS - 1;
  const float sv = Sg[q], tv = Tg[q];

  // prologue: bias image (plain vector copy) + in halves (async)
  #pragma unroll 1
  for (int o = tid * 16; o < 12304; o += 8192)
    *(f32x4*)(smem + 65536 + o) = *(const f32x4*)(ws + WS_BIAS + o);
  stage32(ws + WS_INW,          sAw, wave, lane);
  stage32(ws + WS_INW + 32768u, sBw, wave, lane);
  __syncthreads();

  f16x8 x0,x1,x2,x3,x4,x5,x6,x7;       // x fragments (32 regs)
  f16x8 u0,u1,u2,u3,u4,u5,u6,u7;       // u fragments (32 regs)

  // ---- input layer: x = sin(30*(ff @ in_w + in_b)); trig once, 4 accs
  {
    f32x16 a0,a1,a2,a3;
    BINIT(a0,0,0) BINIT(a1,0,1) BINIT(a2,0,2) BINIT(a3,0,3)
    FFG(0, sA_) FFG(1, sA_) FFG(2, sA_) FFG(3, sA_)
    __syncthreads();
    stage32(ws + WS_W1, sAw, wave, lane);
    FFG(4, sB_) FFG(5, sB_) FFG(6, sB_) FFG(7, sB_)
    __syncthreads();
    stage32(ws + WS_W2, sBw, wave, lane);
    SINPACK(x0,x1,a0) SINPACK(x2,x3,a1) SINPACK(x4,x5,a2) SINPACK(x6,x7,a3)
  }

  // ---- residual blocks
  #pragma unroll 1
  for (int i = 0; i < 8; ++i) {
    const int Mw1 = 1 + 2 * i, Mw2 = 2 + 2 * i;

    __syncthreads();                          // staged sA(w1_i)/sB(w2_i) ready
    W1TILE(0, u0,u1) W1TILE(1, u2,u3) W1TILE(2, u4,u5) W1TILE(3, u6,u7)
    __syncthreads();                          // sA reads done
    if ((i & 1) == 0) stage32(ws + WS_SKIP + (uint32_t)(i >> 1) * 65536u, sAw, wave, lane);
    else if (i < 7)   stage32(ws + WS_W1 + (uint32_t)(i + 1) * 32768u, sAw, wave, lane);

    W2TILE(0, x0,x1) W2TILE(1, x2,x3) W2TILE(2, x4,x5) W2TILE(3, x6,x7)
    __syncthreads();                          // sB reads done
    if ((i & 1) == 0) stage32(ws + WS_SKIP + (uint32_t)(i >> 1) * 65536u + 32768u, sBw, wave, lane);
    else if (i < 7)   stage32(ws + WS_W2 + (uint32_t)(i + 1) * 32768u, sBw, wave, lane);

    if ((i & 1) == 0) {                       // skip from Fourier features
      const int Msk = 17 + (i >> 1);
      __syncthreads();                        // skipA+skipB staged (vmcnt drained)
      f32x16 a0,a1,a2,a3;
      BINIT(a0,Msk,0) BINIT(a1,Msk,1) BINIT(a2,Msk,2) BINIT(a3,Msk,3)
      UNPADD(a0, x0,x1) UNPADD(a1, x2,x3) UNPADD(a2, x4,x5) UNPADD(a3, x6,x7)
      FFG(0, sA_) FFG(1, sA_) FFG(2, sA_) FFG(3, sA_)
      __syncthreads();
      stage32(ws + WS_W1 + (uint32_t)(i + 1) * 32768u, sAw, wave, lane);
      FFG(4, sB_) FFG(5, sB_) FFG(6, sB_) FFG(7, sB_)
      __syncthreads();
      stage32(ws + WS_W2 + (uint32_t)(i + 1) * 32768u, sBw, wave, lane);
      FPACK(x0,x1,a0) FPACK(x2,x3,a1) FPACK(x4,x5,a2) FPACK(x6,x7,a3)
    }
  }

  // ---- output: out = x @ out_w + out_b (2 lanes/pt: fold hi halves)
  float p = 0.0f;
  { const float* bp = biasL + 21 * 128 + 0 * 32 + hi4; OWDOT(p, x0, x1, bp) }
  { const float* bp = biasL + 21 * 128 + 1 * 32 + hi4; OWDOT(p, x2, x3, bp) }
  { const float* bp = biasL + 21 * 128 + 2 * 32 + hi4; OWDOT(p, x4, x5, bp) }
  { const float* bp = biasL + 21 * 128 + 3 * 32 + hi4; OWDOT(p, x6, x7, bp) }
  p += __shfl_xor(p, 32);
  if (hi == 0 && pt < NPTS) outg[pt] = p + biasL[3072];
}

extern "C" void kernel_launch(void* const* d_in, const int* in_sizes, int n_in,
                              void* d_out, int out_size, void* d_ws, size_t ws_size,
                              hipStream_t stream) {
  (void)in_sizes; (void)n_in; (void)out_size;
  const float* S   = (const float*)d_in[0];
  const float* T   = (const float*)d_in[1];
  const float* B   = (const float*)d_in[2];
  const float* inw = (const float*)d_in[3];
  const float* inb = (const float*)d_in[4];
  const float* w1  = (const float*)d_in[5];
  const float* b1  = (const float*)d_in[6];
  const float* w2  = (const float*)d_in[7];
  const float* b2  = (const float*)d_in[8];
  const float* sw  = (const float*)d_in[9];
  const float* sb  = (const float*)d_in[10];
  const float* ow  = (const float*)d_in[11];
  const float* ob  = (const float*)d_in[12];
  char* ws   = (char*)d_ws;
  float* out = (float*)d_out;
  if (ws_size < (size_t)WS_TOTAL) return;

  pinn_prep<<<1677, 256, 0, stream>>>(inw, w1, w2, sw, inb, b1, b2, sb, ow, ob, B, ws);

  const int smem_bytes = 77840;   // 32K + 32K + 12.3K -> 2 blocks/CU
  hipFuncSetAttribute(reinterpret_cast<const void*>(pinn_main),
                      hipFuncAttributeMaxDynamicSharedMemorySize, smem_bytes);
  const int grid = (NPTS + 255) / 256;   // 1954
  pinn_main<<<grid, 512, smem_bytes, stream>>>(S, T, ws, out);
}